// Round 16
// baseline (567.975 us; speedup 1.0000x reference)
//
#include <hip/hip_runtime.h>
#include <cstdint>
#include <cstddef>

// ---------------------------------------------------------------------------
// MambaBlock: x -> x + MLP(LN1(x)) -> (+) mamba(LN2(.))
// B=2 L=2048 d_model=1024 d_inner=4096 d_state=16 d_conv=4 dt_rank=64
// Workspace: ~240 MiB
// R15: fuse conv1d+silu into in_proj's u-half epilogue (C-tile = [256 tok]x
//      [256 ch]; taps are in-tile except first 3 rows -> 768KB raw-u halo
//      side buffer + 32-block fixup kernel). in_proj split u-half/z-half;
//      u-half of xz never written (conv was its only reader). Saves the conv
//      dispatch (64MB traffic) + 32MB store.
// ---------------------------------------------------------------------------

namespace {
constexpr int D_MODEL = 1024;
constexpr int D_INNER = 4096;
constexpr int D_STATE = 16;
constexpr int DT_RANK = 64;
constexpr int B_SZ    = 2;
constexpr int L_SEQ   = 2048;
constexpr int M_ROWS  = B_SZ * L_SEQ;   // 4096 token rows
constexpr int LC      = 32;             // scan chunk length
constexpr int NCHUNK  = L_SEQ / LC;     // 64
}

typedef __bf16 bf16x8_t __attribute__((ext_vector_type(8)));
typedef float  f32x4    __attribute__((ext_vector_type(4)));
typedef unsigned short us8 __attribute__((ext_vector_type(8)));

__device__ __forceinline__ unsigned short f2bf(float f) {
  union { float f; unsigned int u; } v; v.f = f;
  unsigned int r = (v.u + 0x7fffu + ((v.u >> 16) & 1u)) >> 16;
  return (unsigned short)r;
}
__device__ __forceinline__ float bf2f(unsigned short s) {
  union { unsigned int u; float f; } v; v.u = ((unsigned int)s) << 16;
  return v.f;
}

// branchless softplus on HW trans pipe: max(v,0) + ln2*log2(1+exp2(-|v|*log2e))
__device__ __forceinline__ float softplus_fast(float v) {
  const float e = __builtin_amdgcn_exp2f(-fabsf(v) * 1.44269504088896f);
  return fmaxf(v, 0.f) + 0.693147180559945f * __builtin_amdgcn_logf(1.f + e);
}

// async global->LDS, 16B per lane. LDS dest must be wave-uniform base;
// HW writes base + lane*16.
__device__ __forceinline__ void gload16(const void* g, void* l) {
  __builtin_amdgcn_global_load_lds(
      (const __attribute__((address_space(1))) unsigned int*)g,
      (__attribute__((address_space(3))) unsigned int*)l, 16, 0, 0);
}

// ---------------------------------------------------------------------------
// fused f32 -> bf16 cast for all 6 weight tensors (1024 elems / block)
// ---------------------------------------------------------------------------
__global__ __launch_bounds__(256)
void cvt6(const float* __restrict__ s0, unsigned short* __restrict__ d0,
          const float* __restrict__ s1, unsigned short* __restrict__ d1,
          const float* __restrict__ s2, unsigned short* __restrict__ d2,
          const float* __restrict__ s3, unsigned short* __restrict__ d3,
          const float* __restrict__ s4, unsigned short* __restrict__ d4,
          const float* __restrict__ s5, unsigned short* __restrict__ d5) {
  int blk = blockIdx.x;
  const float* s; unsigned short* d;
  if (blk < 4096)                  { s = s0; d = d0; }
  else if ((blk -= 4096) < 4096)   { s = s1; d = d1; }
  else if ((blk -= 4096) < 8192)   { s = s2; d = d2; }
  else if ((blk -= 8192) < 384)    { s = s3; d = d3; }
  else if ((blk -= 384) < 256)     { s = s4; d = d4; }
  else { blk -= 256;                 s = s5; d = d5; }
  const int i = blk * 1024 + threadIdx.x * 4;
  float4 v = *(const float4*)(s + i);
  ushort4 o; o.x = f2bf(v.x); o.y = f2bf(v.y); o.z = f2bf(v.z); o.w = f2bf(v.w);
  *(ushort4*)(d + i) = o;
}

// ---------------------------------------------------------------------------
// LayerNorm over D_MODEL=1024; one block (256 thr) per row; bf16 out
// ---------------------------------------------------------------------------
__global__ __launch_bounds__(256) void ln_bf16(const float* __restrict__ x,
                                               const float* __restrict__ g,
                                               const float* __restrict__ b,
                                               unsigned short* __restrict__ out) {
  const int row = blockIdx.x;
  const int tid = threadIdx.x;
  const float4 v = *(const float4*)(x + (size_t)row * D_MODEL + tid * 4);
  float s  = v.x + v.y + v.z + v.w;
  float s2 = v.x*v.x + v.y*v.y + v.z*v.z + v.w*v.w;
#pragma unroll
  for (int o = 32; o >= 1; o >>= 1) { s += __shfl_xor(s, o); s2 += __shfl_xor(s2, o); }
  __shared__ float red[8];
  if ((tid & 63) == 0) { red[(tid >> 6) * 2] = s; red[(tid >> 6) * 2 + 1] = s2; }
  __syncthreads();
  s  = red[0] + red[2] + red[4] + red[6];
  s2 = red[1] + red[3] + red[5] + red[7];
  const float mu  = s * (1.f / D_MODEL);
  const float var = s2 * (1.f / D_MODEL) - mu * mu;
  const float rstd = rsqrtf(var + 1e-5f);
  const float4 gv = *(const float4*)(g + tid * 4);
  const float4 bv = *(const float4*)(b + tid * 4);
  ushort4 o;
  o.x = f2bf((v.x - mu) * rstd * gv.x + bv.x);
  o.y = f2bf((v.y - mu) * rstd * gv.y + bv.y);
  o.z = f2bf((v.z - mu) * rstd * gv.z + bv.z);
  o.w = f2bf((v.w - mu) * rstd * gv.w + bv.w);
  *(ushort4*)(out + (size_t)row * D_MODEL + tid * 4) = o;
}

// ---------------------------------------------------------------------------
// fused: x2 = sum4(MLP2 bf16 partials) + bias2 + x ; xn = LN(x2) bf16
// ---------------------------------------------------------------------------
__global__ __launch_bounds__(256)
void combine_ln(const unsigned short* __restrict__ part, const float* __restrict__ bias,
                const float* __restrict__ res, const float* __restrict__ g,
                const float* __restrict__ b, float* __restrict__ x2out,
                unsigned short* __restrict__ xnout) {
  const int row = blockIdx.x;
  const int tid = threadIdx.x;
  const size_t i4 = (size_t)row * D_MODEL + tid * 4;
  constexpr size_t S = (size_t)M_ROWS * D_MODEL;
  float a0 = 0.f, a1 = 0.f, a2 = 0.f, a3 = 0.f;
#pragma unroll
  for (int z = 0; z < 4; ++z) {
    const ushort4 p = *(const ushort4*)(part + z * S + i4);
    a0 += bf2f(p.x); a1 += bf2f(p.y); a2 += bf2f(p.z); a3 += bf2f(p.w);
  }
  const float4 bv = *(const float4*)(bias + tid * 4);
  const float4 rv = *(const float4*)(res + i4);
  float4 v;
  v.x = a0 + bv.x + rv.x;
  v.y = a1 + bv.y + rv.y;
  v.z = a2 + bv.z + rv.z;
  v.w = a3 + bv.w + rv.w;
  *(float4*)(x2out + i4) = v;
  float s  = v.x + v.y + v.z + v.w;
  float s2 = v.x*v.x + v.y*v.y + v.z*v.z + v.w*v.w;
#pragma unroll
  for (int o = 32; o >= 1; o >>= 1) { s += __shfl_xor(s, o); s2 += __shfl_xor(s2, o); }
  __shared__ float red[8];
  if ((tid & 63) == 0) { red[(tid >> 6) * 2] = s; red[(tid >> 6) * 2 + 1] = s2; }
  __syncthreads();
  s  = red[0] + red[2] + red[4] + red[6];
  s2 = red[1] + red[3] + red[5] + red[7];
  const float mu  = s * (1.f / D_MODEL);
  const float var = s2 * (1.f / D_MODEL) - mu * mu;
  const float rstd = rsqrtf(var + 1e-5f);
  const float4 gv = *(const float4*)(g + tid * 4);
  const float4 b2 = *(const float4*)(b + tid * 4);
  ushort4 o;
  o.x = f2bf((v.x - mu) * rstd * gv.x + b2.x);
  o.y = f2bf((v.y - mu) * rstd * gv.y + b2.y);
  o.z = f2bf((v.z - mu) * rstd * gv.z + b2.z);
  o.w = f2bf((v.w - mu) * rstd * gv.w + b2.w);
  *(ushort4*)(xnout + i4) = o;
}

// ---------------------------------------------------------------------------
// 256x256-tile 8-wave bf16 GEMM, BK=64, read-once fragments + LDS-staged
// coalesced epilogue. (R14 no-pins structure = measured best.)
// EPI: 0 silu(v+bias)->bf16 | 2 v->bf16 (non-temporal)
//      3 conv1d(k=4)+silu fused epilogue -> uc (+ raw-u halo rows -> uside)
//      8 v->bf16 partial (split-K via blockIdx.z, chunk K elems at z*K)
// ldc = output row stride. M%256==0, N%256==0, K%64==0.
// ---------------------------------------------------------------------------
template<int EPI>
__global__ __launch_bounds__(512, 1)
void gemm256(const unsigned short* __restrict__ A, const unsigned short* __restrict__ W,
             int M, int N, int K, int lda, int ldw, int ldc,
             const float* __restrict__ bias, void* __restrict__ out0,
             const float* __restrict__ cw, const float* __restrict__ cb,
             unsigned short* __restrict__ uside) {
  if constexpr (EPI == 8) {
    const size_t koff = (size_t)blockIdx.z * K;
    A += koff; W += koff;
    out0 = (void*)((unsigned short*)out0 + (size_t)blockIdx.z * M * ldc);
  }
  __shared__ unsigned short smem[65536];  // As[2]:0..32767, Bs[2]:32768..65535
  const int tid  = threadIdx.x;
  const int w    = tid >> 6;
  const int lane = tid & 63;
  const int wr = w >> 2;            // 0..1 : wave row  (128 rows of C)
  const int wc = w & 3;             // 0..3 : wave col  (64 cols of C)
  const int fr = lane & 15;
  const int fq = lane >> 4;         // 0..3

  // XCD-aware chunked swizzle (nwg % 8 == 0)
  const int gx = gridDim.x, gy = gridDim.y;
  const int nwg = gx * gy;
  const int id  = blockIdx.y * gx + blockIdx.x;
  const int wid = (id & 7) * (nwg >> 3) + (id >> 3);
  const int n0 = (wid / gy) * 256;
  const int m0 = (wid % gy) * 256;

  // staging indices: 512 threads; line = 64 rows x 64 k (8 KB); 4 lines/operand
  const int srow  = tid >> 3;                       // 0..63 row within line
  const int skelem = ((tid & 7) ^ (srow & 7)) * 8;  // pre-swizzled k-offset

  // read-side swizzled slot offsets (elements), per-lane constant
  int aslot[2];
#pragma unroll
  for (int ks = 0; ks < 2; ++ks) aslot[ks] = ((ks * 4 + fq) ^ (fr & 7)) * 8;

  f32x4 acc[8][4];
#pragma unroll
  for (int m = 0; m < 8; ++m)
#pragma unroll
    for (int n = 0; n < 4; ++n) acc[m][n] = f32x4{0.f, 0.f, 0.f, 0.f};

  const int NT = K >> 6;

  auto STAGE_HALF = [&](int half, int tn, unsigned short* Ad, unsigned short* Bd) {
    const int k0 = tn * 64;
    if (half < 2) {
#pragma unroll
      for (int li = 0; li < 2; ++li) {
        const int l = half * 2 + li;
        gload16(A + (size_t)(m0 + l * 64 + srow) * lda + k0 + skelem,
                Ad + (l * 64 + w * 8) * 64);
      }
    } else {
#pragma unroll
      for (int li = 0; li < 2; ++li) {
        const int l = (half - 2) * 2 + li;
        gload16(W + (size_t)(n0 + l * 64 + srow) * ldw + k0 + skelem,
                Bd + (l * 64 + w * 8) * 64);
      }
    }
  };

  // prologue: stage tile 0 -> buf 0
#pragma unroll
  for (int h = 0; h < 4; ++h) STAGE_HALF(h, 0, smem, smem + 32768);
  asm volatile("s_waitcnt vmcnt(0)" ::: "memory");
  __builtin_amdgcn_s_barrier();

  for (int t = 0; t < NT; ++t) {
    const int cur = t & 1;
    const unsigned short* Ab = smem + cur * 16384;
    const unsigned short* Bb = smem + 32768 + cur * 16384;
    unsigned short* Adn = smem + (cur ^ 1) * 16384;
    unsigned short* Bdn = smem + 32768 + (cur ^ 1) * 16384;
    const bool more = (t + 1 < NT);

    bf16x8_t af[4][2], bflo[2][2], bfhi[2][2];

    // ---- phase 0: quadrant (0,0). read af_lo + bf_lo; stage halves 0,1
#pragma unroll
    for (int mfi = 0; mfi < 4; ++mfi)
#pragma unroll
      for (int ks = 0; ks < 2; ++ks)
        af[mfi][ks] = *(const bf16x8_t*)
            &Ab[(wr * 128 + mfi * 16 + fr) * 64 + aslot[ks]];
#pragma unroll
    for (int nfi = 0; nfi < 2; ++nfi)
#pragma unroll
      for (int ks = 0; ks < 2; ++ks)
        bflo[nfi][ks] = *(const bf16x8_t*)
            &Bb[(wc * 64 + nfi * 16 + fr) * 64 + aslot[ks]];
    if (more) { STAGE_HALF(0, t + 1, Adn, Bdn); STAGE_HALF(1, t + 1, Adn, Bdn); }
    asm volatile("s_waitcnt lgkmcnt(0)" ::: "memory");
    __builtin_amdgcn_s_barrier();
    __builtin_amdgcn_s_setprio(1);
#pragma unroll
    for (int mfi = 0; mfi < 4; ++mfi)
#pragma unroll
      for (int nfi = 0; nfi < 2; ++nfi)
#pragma unroll
        for (int ks = 0; ks < 2; ++ks)
          acc[mfi][nfi] = __builtin_amdgcn_mfma_f32_16x16x32_bf16(
              af[mfi][ks], bflo[nfi][ks], acc[mfi][nfi], 0, 0, 0);
    __builtin_amdgcn_s_setprio(0);

    // ---- phase 1: quadrant (0,1). read bf_hi; stage halves 2,3
#pragma unroll
    for (int nfi = 0; nfi < 2; ++nfi)
#pragma unroll
      for (int ks = 0; ks < 2; ++ks)
        bfhi[nfi][ks] = *(const bf16x8_t*)
            &Bb[(wc * 64 + (2 + nfi) * 16 + fr) * 64 + aslot[ks]];
    if (more) { STAGE_HALF(2, t + 1, Adn, Bdn); STAGE_HALF(3, t + 1, Adn, Bdn); }
    asm volatile("s_waitcnt lgkmcnt(0)" ::: "memory");
    __builtin_amdgcn_s_barrier();
    __builtin_amdgcn_s_setprio(1);
#pragma unroll
    for (int mfi = 0; mfi < 4; ++mfi)
#pragma unroll
      for (int nfi = 0; nfi < 2; ++nfi)
#pragma unroll
        for (int ks = 0; ks < 2; ++ks)
          acc[mfi][2 + nfi] = __builtin_amdgcn_mfma_f32_16x16x32_bf16(
              af[mfi][ks], bfhi[nfi][ks], acc[mfi][2 + nfi], 0, 0, 0);
    __builtin_amdgcn_s_setprio(0);

    // ---- phase 2: quadrant (1,0). read af_hi into af regs (time-share)
#pragma unroll
    for (int mfi = 0; mfi < 4; ++mfi)
#pragma unroll
      for (int ks = 0; ks < 2; ++ks)
        af[mfi][ks] = *(const bf16x8_t*)
            &Ab[(wr * 128 + (4 + mfi) * 16 + fr) * 64 + aslot[ks]];
    asm volatile("s_waitcnt lgkmcnt(0)" ::: "memory");
    __builtin_amdgcn_s_barrier();
    __builtin_amdgcn_s_setprio(1);
#pragma unroll
    for (int mfi = 0; mfi < 4; ++mfi)
#pragma unroll
      for (int nfi = 0; nfi < 2; ++nfi)
#pragma unroll
        for (int ks = 0; ks < 2; ++ks)
          acc[4 + mfi][nfi] = __builtin_amdgcn_mfma_f32_16x16x32_bf16(
              af[mfi][ks], bflo[nfi][ks], acc[4 + mfi][nfi], 0, 0, 0);
    __builtin_amdgcn_s_setprio(0);

    // ---- phase 3: quadrant (1,1). no ds_reads.
    __builtin_amdgcn_s_setprio(1);
#pragma unroll
    for (int mfi = 0; mfi < 4; ++mfi)
#pragma unroll
      for (int nfi = 0; nfi < 2; ++nfi)
#pragma unroll
        for (int ks = 0; ks < 2; ++ks)
          acc[4 + mfi][2 + nfi] = __builtin_amdgcn_mfma_f32_16x16x32_bf16(
              af[mfi][ks], bfhi[nfi][ks], acc[4 + mfi][2 + nfi], 0, 0, 0);
    __builtin_amdgcn_s_setprio(0);

    // K-tile boundary: drain next tile's staging, release both buffers
    asm volatile("s_waitcnt vmcnt(0)" ::: "memory");
    __builtin_amdgcn_s_barrier();
  }

  // ---- LDS-staged coalesced epilogue: smem reused as C[256][256] bf16 ----
  unsigned short* Cs = smem;
#pragma unroll
  for (int mf = 0; mf < 8; ++mf)
#pragma unroll
    for (int nf = 0; nf < 4; ++nf)
#pragma unroll
      for (int j = 0; j < 4; ++j) {
        const int row = wr * 128 + mf * 16 + fq * 4 + j;
        const int col = wc * 64 + nf * 16 + fr;
        float v = acc[mf][nf][j];
        if constexpr (EPI == 0) {
          v += bias[n0 + col];
          v = v / (1.f + __expf(-v));
        }
        Cs[row * 256 + ((((col >> 3) ^ (row & 7)) << 3) | (col & 7))] = f2bf(v);
      }
  __syncthreads();
  unsigned short* outp = (unsigned short*)out0;
  const int trow = tid >> 5;        // 0..15
  const int tg   = tid & 31;        // col group
  auto ldrow = [&](int r) -> us8 {
    const int rr = r < 0 ? 0 : r;
    return *(const us8*)&Cs[rr * 256 + ((tg ^ (rr & 7)) << 3)];
  };
#pragma unroll
  for (int i = 0; i < 16; ++i) {
    const int row = i * 16 + trow;
    const us8 vv = ldrow(row);
    if constexpr (EPI == 3) {
      // raw-u halo rows -> side buffer for the fixup kernel
      if (row < 3 || row >= 253) {
        const int sel = row < 3 ? row : row - 250;
        *(us8*)&uside[(((size_t)(m0 >> 8) * 6 + sel) * 4096) + n0 + tg * 8] = vv;
      }
      const us8 vm1 = ldrow(row - 1);
      const us8 vm2 = ldrow(row - 2);
      const us8 vm3 = ldrow(row - 3);
      us8 o;
#pragma unroll
      for (int j = 0; j < 8; ++j) {
        const int ch = n0 + tg * 8 + j;
        const float4 w4 = *(const float4*)(cw + ch * 4);
        float a = cb[ch];
        a += bf2f(vm3[j]) * w4.x + bf2f(vm2[j]) * w4.y +
             bf2f(vm1[j]) * w4.z + bf2f(vv[j]) * w4.w;
        o[j] = f2bf(a / (1.f + __expf(-a)));
      }
      *(us8*)&outp[(size_t)(m0 + row) * ldc + n0 + tg * 8] = o;
    } else {
      unsigned short* dst = &outp[(size_t)(m0 + row) * ldc + n0 + tg * 8];
      if constexpr (EPI == 2) __builtin_nontemporal_store(vv, (us8*)dst);
      else                    *(us8*)dst = vv;
    }
  }
}

// ---------------------------------------------------------------------------
// conv fixup: redo conv+silu for rows m0..m0+2 of each 256-token tile using
// the raw-u halo side buffer. l<3 (sequence starts, tiles 0 and 8) zero-pad.
// grid 32 x 256 threads = 16 tiles x 512 ch-groups.
// ---------------------------------------------------------------------------
__global__ __launch_bounds__(256)
void conv_fixup(const unsigned short* __restrict__ uside, const float* __restrict__ cw,
                const float* __restrict__ cb, unsigned short* __restrict__ uc) {
  const int idx = blockIdx.x * 256 + threadIdx.x;
  const int tm = idx >> 9;            // tile 0..15
  const int g8 = (idx & 511) * 8;     // channel group base
  const int m0 = tm << 8;
  auto sideld = [&](int t, int sel) -> us8 {
    return *(const us8*)&uside[(((size_t)t * 6 + sel) * 4096) + g8];
  };
  const us8 zero = {0, 0, 0, 0, 0, 0, 0, 0};
  us8 cur[3];
  cur[0] = sideld(tm, 0); cur[1] = sideld(tm, 1); cur[2] = sideld(tm, 2);
  us8 p3 = zero, p4 = zero, p5 = zero;
  const bool seqstart = ((m0 & (L_SEQ - 1)) == 0);
  if (!seqstart) { p3 = sideld(tm - 1, 3); p4 = sideld(tm - 1, 4); p5 = sideld(tm - 1, 5); }
#pragma unroll
  for (int r = 0; r < 3; ++r) {
    const int l = (m0 & (L_SEQ - 1)) + r;
    const us8 t3v = cur[r];
    const us8 t2v = (l >= 1) ? (r >= 1 ? cur[r - 1] : p5) : zero;
    const us8 t1v = (l >= 2) ? (r >= 2 ? cur[0] : (r == 1 ? p5 : p4)) : zero;
    const us8 t0v = (l >= 3) ? (r == 2 ? p5 : (r == 1 ? p4 : p3)) : zero;
    us8 o;
#pragma unroll
    for (int j = 0; j < 8; ++j) {
      const int ch = g8 + j;
      const float4 w4 = *(const float4*)(cw + ch * 4);
      float a = cb[ch];
      a += bf2f(t0v[j]) * w4.x + bf2f(t1v[j]) * w4.y +
           bf2f(t2v[j]) * w4.z + bf2f(t3v[j]) * w4.w;
      o[j] = f2bf(a / (1.f + __expf(-a)));
    }
    *(us8*)&uc[(size_t)(m0 + r) * D_INNER + g8] = o;
  }
}

// ---------------------------------------------------------------------------
// 128x128 2-phase bf16 GEMM (small shapes) + LDS-staged epilogue for bf16.
// EPI: 4 softplus(v+bias)->bf16 | 6 v->f32 partial (split-K via blockIdx.z)
// ---------------------------------------------------------------------------
template<int EPI>
__global__ __launch_bounds__(256)
void gemm_bt(const unsigned short* __restrict__ A, const unsigned short* __restrict__ W,
             int M, int N, int K, int lda, int ldw, int ldc,
             const float* __restrict__ bias, const float* __restrict__ res,
             void* __restrict__ out0) {
  if constexpr (EPI == 6) {
    const size_t koff = (size_t)blockIdx.z * K;
    A += koff; W += koff;
    out0 = (void*)((float*)out0 + (size_t)blockIdx.z * M * ldc);
  }
  const int gx = gridDim.x, gy = gridDim.y;
  const int nwg = gx * gy;
  const int id  = blockIdx.y * gx + blockIdx.x;
  const int wid = (nwg >= 8) ? ((id & 7) * (nwg >> 3) + (id >> 3)) : id;
  const int n0 = (wid / gy) * 128;
  const int m0 = (wid % gy) * 128;

  __shared__ unsigned short smem[16384];  // As[2]:0..8191, Bs[2]:8192..16383
  const int tid  = threadIdx.x;
  const int w    = tid >> 6;
  const int lane = tid & 63;
  const int wm = (w >> 1) * 64;
  const int wn = (w & 1) * 64;
  const int lrow = lane >> 2;
  const int lkb  = (lane & 3) * 8;
  const int fr   = lane & 15;
  const int fq   = lane >> 4;

  f32x4 acc[4][4];
#pragma unroll
  for (int m = 0; m < 4; ++m)
#pragma unroll
    for (int n = 0; n < 4; ++n) acc[m][n] = f32x4{0.f, 0.f, 0.f, 0.f};

  const int ar0 = m0 + (w * 2 + 0) * 16 + lrow;
  const int ar1 = m0 + (w * 2 + 1) * 16 + lrow;
  int br0 = n0 + (w * 2 + 0) * 16 + lrow; if (br0 > N - 1) br0 = N - 1;
  int br1 = n0 + (w * 2 + 1) * 16 + lrow; if (br1 > N - 1) br1 = N - 1;

  const int nk = K >> 5;
  auto STAGE = [&](int buf, int kt) {
    const int k0 = kt * 32;
    gload16(A + (size_t)ar0 * lda + k0 + lkb, smem + buf * 4096 + (w * 2 + 0) * 512);
    gload16(A + (size_t)ar1 * lda + k0 + lkb, smem + buf * 4096 + (w * 2 + 1) * 512);
    gload16(W + (size_t)br0 * ldw + k0 + lkb, smem + 8192 + buf * 4096 + (w * 2 + 0) * 512);
    gload16(W + (size_t)br1 * ldw + k0 + lkb, smem + 8192 + buf * 4096 + (w * 2 + 1) * 512);
  };
  STAGE(0, 0);
  if (nk > 1) STAGE(1, 1);

  for (int kt = 0; kt < nk; ++kt) {
    const int cur = kt & 1;
    if (kt + 1 < nk) asm volatile("s_waitcnt vmcnt(4)" ::: "memory");
    else             asm volatile("s_waitcnt vmcnt(0)" ::: "memory");
    __builtin_amdgcn_s_barrier();
    const unsigned short* Ac = smem + cur * 4096;
    const unsigned short* Bc = smem + 8192 + cur * 4096;
    bf16x8_t af[4], bf[4];
#pragma unroll
    for (int m = 0; m < 4; ++m) af[m] = *(const bf16x8_t*)&Ac[(wm + m * 16 + fr) * 32 + fq * 8];
#pragma unroll
    for (int n = 0; n < 4; ++n) bf[n] = *(const bf16x8_t*)&Bc[(wn + n * 16 + fr) * 32 + fq * 8];
    __builtin_amdgcn_s_setprio(1);
#pragma unroll
    for (int m = 0; m < 4; ++m)
#pragma unroll
      for (int n = 0; n < 4; ++n)
        acc[m][n] = __builtin_amdgcn_mfma_f32_16x16x32_bf16(af[m], bf[n], acc[m][n], 0, 0, 0);
    __builtin_amdgcn_s_setprio(0);
    asm volatile("s_waitcnt lgkmcnt(0)" ::: "memory");
    __builtin_amdgcn_s_barrier();
    if (kt + 2 < nk) STAGE(cur, kt + 2);
  }

  if constexpr (EPI == 6) {
#pragma unroll
    for (int m = 0; m < 4; ++m)
#pragma unroll
      for (int n = 0; n < 4; ++n)
#pragma unroll
        for (int j = 0; j < 4; ++j) {
          const int r = m0 + wm + m * 16 + fq * 4 + j;
          const int c = n0 + wn + n * 16 + fr;
          if (c >= N) continue;
          ((float*)out0)[(size_t)r * ldc + c] = acc[m][n][j];
        }
  } else {
    // LDS-staged coalesced epilogue: smem reused as C[128][128] bf16
    unsigned short* Cs = smem;
#pragma unroll
    for (int m = 0; m < 4; ++m)
#pragma unroll
      for (int n = 0; n < 4; ++n)
#pragma unroll
        for (int j = 0; j < 4; ++j) {
          const int row = wm + m * 16 + fq * 4 + j;
          const int col = wn + n * 16 + fr;
          float v = acc[m][n][j];
          if constexpr (EPI == 4) v = softplus_fast(v + bias[n0 + col]);
          Cs[row * 128 + ((((col >> 3) ^ (row & 7)) << 3) | (col & 7))] = f2bf(v);
        }
    __syncthreads();
    unsigned short* outp = (unsigned short*)out0;
    const int trow = tid >> 4;        // 0..15
    const int tg   = tid & 15;        // col group
#pragma unroll
    for (int i = 0; i < 8; ++i) {
      const int row = i * 16 + trow;
      const us8 vv = *(const us8*)&Cs[row * 128 + ((tg ^ (row & 7)) << 3)];
      *(us8*)&outp[(size_t)(m0 + row) * ldc + n0 + tg * 8] = vv;
    }
  }
}

// ---------------------------------------------------------------------------
// split-K x4 combiner (bf16 partials): out = sum4 + res  (out_proj epilogue)
// ---------------------------------------------------------------------------
__global__ __launch_bounds__(256)
void splitk_combine_bf(const unsigned short* __restrict__ part,
                       const float* __restrict__ res, float* __restrict__ out) {
  const size_t i4 = ((size_t)blockIdx.x * 256 + threadIdx.x) * 4;
  constexpr size_t S = (size_t)M_ROWS * D_MODEL;
  float a0 = 0.f, a1 = 0.f, a2 = 0.f, a3 = 0.f;
#pragma unroll
  for (int z = 0; z < 4; ++z) {
    const ushort4 p = *(const ushort4*)(part + z * S + i4);
    a0 += bf2f(p.x); a1 += bf2f(p.y); a2 += bf2f(p.z); a3 += bf2f(p.w);
  }
  const float4 r = *(const float4*)(res + i4);
  *(float4*)(out + i4) = float4{a0 + r.x, a1 + r.y, a2 + r.z, a3 + r.w};
}

// ---------------------------------------------------------------------------
// split-K combiner for x_proj: part[8][4096][96] -> dt_in(bf16), Bm, Cm (f32)
// ---------------------------------------------------------------------------
__global__ __launch_bounds__(256)
void xproj_combine(const float* __restrict__ part, unsigned short* __restrict__ dtin,
                   float* __restrict__ Bm, float* __restrict__ Cm) {
  const int idx = blockIdx.x * 256 + threadIdx.x;  // 4096*96
  const int r = idx / 96, c = idx - r * 96;
  constexpr size_t S = (size_t)M_ROWS * 96;
  float v = 0.f;
#pragma unroll
  for (int z = 0; z < 8; ++z) v += part[idx + z * S];
  if (c < DT_RANK)            dtin[(size_t)r * DT_RANK + c] = f2bf(v);
  else if (c < DT_RANK + 16)  Bm[(size_t)r * 16 + (c - DT_RANK)] = v;
  else                        Cm[(size_t)r * 16 + (c - DT_RANK - 16)] = v;
}

// ---------------------------------------------------------------------------
// Chunk-parallel selective scan, LC=32 (diagonal dA => chunk composes as
// h = P*h_in + Q, P = exp(A*sum_dt)). Thread owns one channel d: h[16] regs.
// ---------------------------------------------------------------------------
__global__ __launch_bounds__(128)
void scan_part(const unsigned short* __restrict__ dt, const unsigned short* __restrict__ uc,
               const float* __restrict__ Bm, const float* __restrict__ A_log,
               float* __restrict__ Q, float* __restrict__ sumdt) {
  __shared__ float sB[LC][D_STATE];
  const int lt = threadIdx.x;
  const int d  = blockIdx.x * 128 + lt;
  const int c  = blockIdx.y;
  const int b  = blockIdx.z;
  const size_t rowbase = (size_t)b * L_SEQ + (size_t)c * LC;
  ((float4*)&sB[0][0])[lt] = ((const float4*)(Bm + rowbase * D_STATE))[lt];
  float Ap[D_STATE];
#pragma unroll
  for (int s = 0; s < D_STATE; ++s)
    Ap[s] = -__expf(A_log[d * D_STATE + s]) * 1.44269504088896f;
  float h[D_STATE];
#pragma unroll
  for (int s = 0; s < D_STATE; ++s) h[s] = 0.f;
  float sdt = 0.f;
  __syncthreads();
  for (int t = 0; t < LC; ++t) {
    const size_t row = rowbase + t;
    const float dtv = bf2f(dt[row * D_INNER + d]);
    const float uv  = bf2f(uc[row * D_INNER + d]);
    sdt += dtv;
    const float du = dtv * uv;
    const float4* bp = (const float4*)&sB[t][0];
    const float4 b0 = bp[0], b1 = bp[1], b2 = bp[2], b3 = bp[3];
    const float Bv[16] = {b0.x,b0.y,b0.z,b0.w, b1.x,b1.y,b1.z,b1.w,
                          b2.x,b2.y,b2.z,b2.w, b3.x,b3.y,b3.z,b3.w};
#pragma unroll
    for (int s = 0; s < D_STATE; ++s) {
      const float dA = __builtin_amdgcn_exp2f(dtv * Ap[s]);
      h[s] = fmaf(dA, h[s], du * Bv[s]);
    }
  }
  float* q = Q + ((((size_t)b * NCHUNK + c) * D_INNER + d) << 4);
#pragma unroll
  for (int s = 0; s < D_STATE; s += 4)
    *(float4*)(q + s) = float4{h[s], h[s+1], h[s+2], h[s+3]};
  sumdt[((size_t)b * NCHUNK + c) * D_INNER + d] = sdt;
}

__global__ __launch_bounds__(256)
void scan_carry(float* __restrict__ Q, const float* __restrict__ sumdt,
                const float* __restrict__ A_log) {
  const int idx = blockIdx.x * 256 + threadIdx.x;   // (b,d,s)
  const int s = idx & 15;
  const int d = (idx >> 4) & (D_INNER - 1);
  const int b = idx >> 16;
  const float Ap = -__expf(A_log[d * D_STATE + s]) * 1.44269504088896f;
  float h = 0.f;
  for (int c = 0; c < NCHUNK; ++c) {
    const size_t base = ((size_t)b * NCHUNK + c) * D_INNER;
    const size_t qoff = ((base + d) << 4) + s;
    const float q = Q[qoff];
    const float P = __builtin_amdgcn_exp2f(sumdt[base + d] * Ap);
    Q[qoff] = h;
    h = fmaf(P, h, q);
  }
}

__global__ __launch_bounds__(128)
void scan_final(const unsigned short* __restrict__ dt, const unsigned short* __restrict__ uc,
                const float* __restrict__ Bm, const float* __restrict__ Cm,
                unsigned short* __restrict__ xz, const float* __restrict__ A_log,
                const float* __restrict__ Dvec, const float* __restrict__ Hin) {
  __shared__ float sB[LC][D_STATE];
  __shared__ float sC[LC][D_STATE];
  const int lt = threadIdx.x;
  const int d  = blockIdx.x * 128 + lt;
  const int c  = blockIdx.y;
  const int b  = blockIdx.z;
  const size_t rowbase = (size_t)b * L_SEQ + (size_t)c * LC;
  ((float4*)&sB[0][0])[lt] = ((const float4*)(Bm + rowbase * D_STATE))[lt];
  ((float4*)&sC[0][0])[lt] = ((const float4*)(Cm + rowbase * D_STATE))[lt];
  float Ap[D_STATE];
#pragma unroll
  for (int s = 0; s < D_STATE; ++s)
    Ap[s] = -__expf(A_log[d * D_STATE + s]) * 1.44269504088896f;
  float h[D_STATE];
  const float* hin = Hin + ((((size_t)b * NCHUNK + c) * D_INNER + d) << 4);
#pragma unroll
  for (int s = 0; s < D_STATE; s += 4) {
    const float4 hv = *(const float4*)(hin + s);
    h[s] = hv.x; h[s+1] = hv.y; h[s+2] = hv.z; h[s+3] = hv.w;
  }
  const float Dv = Dvec[d];
  __syncthreads();
  for (int t = 0; t < LC; ++t) {
    const size_t row = rowbase + t;
    const float dtv = bf2f(dt[row * D_INNER + d]);
    const float uv  = bf2f(uc[row * D_INNER + d]);
    const float zv  = bf2f(xz[row * (2 * D_INNER) + D_INNER + d]);
    const float du = dtv * uv;
    const float4* bp = (const float4*)&sB[t][0];
    const float4 b0 = bp[0], b1 = bp[1], b2 = bp[2], b3 = bp[3];
    const float Bv[16] = {b0.x,b0.y,b0.z,b0.w, b1.x,b1.y,b1.z,b1.w,
                          b2.x,b2.y,b2.z,b2.w, b3.x,b3.y,b3.z,b3.w};
    const float4* cp = (const float4*)&sC[t][0];
    const float4 c0 = cp[0], c1 = cp[1], c2 = cp[2], c3 = cp[3];
    const float Cv[16] = {c0.x,c0.y,c0.z,c0.w, c1.x,c1.y,c1.z,c1.w,
                          c2.x,c2.y,c2.z,c2.w, c3.x,c3.y,c3.z,c3.w};
    float y0 = 0.f, y1 = 0.f;
#pragma unroll
    for (int s = 0; s < D_STATE; s += 2) {
      const float dA0 = __builtin_amdgcn_exp2f(dtv * Ap[s]);
      const float dA1 = __builtin_amdgcn_exp2f(dtv * Ap[s+1]);
      h[s]   = fmaf(dA0, h[s],   du * Bv[s]);
      h[s+1] = fmaf(dA1, h[s+1], du * Bv[s+1]);
      y0 = fmaf(h[s],   Cv[s],   y0);
      y1 = fmaf(h[s+1], Cv[s+1], y1);
    }
    const float yo = (y0 + y1 + uv * Dv) * (zv / (1.f + __expf(-zv)));
    xz[row * (2 * D_INNER) + d] = f2bf(yo);
  }
}

// ---------------------------------------------------------------------------
extern "C" void kernel_launch(void* const* d_in, const int* in_sizes, int n_in,
                              void* d_out, int out_size, void* d_ws, size_t ws_size,
                              hipStream_t stream) {
  (void)in_sizes; (void)n_in; (void)out_size; (void)ws_size;
  const float* x     = (const float*)d_in[0];
  const float* g1    = (const float*)d_in[1];
  const float* b1    = (const float*)d_in[2];
  const float* g2    = (const float*)d_in[3];
  const float* b2    = (const float*)d_in[4];
  const float* w1    = (const float*)d_in[5];
  const float* bias1 = (const float*)d_in[6];
  const float* w2    = (const float*)d_in[7];
  const float* bias2 = (const float*)d_in[8];
  const float* ipw   = (const float*)d_in[9];
  const float* cw    = (const float*)d_in[10];
  const float* cb    = (const float*)d_in[11];
  const float* xpw   = (const float*)d_in[12];
  const float* dtw   = (const float*)d_in[13];
  const float* dtbv  = (const float*)d_in[14];
  const float* A_log = (const float*)d_in[15];
  const float* Dvec  = (const float*)d_in[16];
  const float* opw   = (const float*)d_in[17];

  char* ws = (char*)d_ws;
  size_t off = 0;
  auto alloc = [&](size_t bytes) { void* p = ws + off; off = (off + bytes + 255) & ~(size_t)255; return p; };

  // weights (41.25 MiB)
  unsigned short* w1b  = (unsigned short*)alloc((size_t)D_INNER * D_MODEL * 2);
  unsigned short* w2b  = (unsigned short*)alloc((size_t)D_MODEL * D_INNER * 2);
  unsigned short* ipb  = (unsigned short*)alloc((size_t)2 * D_INNER * D_MODEL * 2);
  unsigned short* xpb  = (unsigned short*)alloc((size_t)96 * D_INNER * 2);
  unsigned short* dtb  = (unsigned short*)alloc((size_t)D_INNER * DT_RANK * 2);
  unsigned short* opb  = (unsigned short*)alloc((size_t)D_MODEL * D_INNER * 2);
  // activations
  unsigned short* xn   = (unsigned short*)alloc((size_t)M_ROWS * D_MODEL * 2);     // 8 MiB
  unsigned short* hid  = (unsigned short*)alloc((size_t)M_ROWS * D_INNER * 2);     // 32 MiB
  float*          x2   = (float*)alloc((size_t)M_ROWS * D_MODEL * 4);              // 16 MiB
  unsigned short* xz   = (unsigned short*)alloc((size_t)M_ROWS * 2 * D_INNER * 2); // 64 MiB
  unsigned short* dtbf = (unsigned short*)alloc((size_t)M_ROWS * D_INNER * 2);     // 32 MiB
  unsigned short* dtin = (unsigned short*)alloc((size_t)M_ROWS * DT_RANK * 2);
  float*          Bmb  = (float*)alloc((size_t)M_ROWS * 16 * 4);
  float*          Cmb  = (float*)alloc((size_t)M_ROWS * 16 * 4);
  float*          xpart= (float*)alloc((size_t)8 * M_ROWS * 96 * 4);               // 12.6 MiB
  float*          Qbuf = (float*)alloc((size_t)B_SZ * NCHUNK * D_INNER * 16 * 4);  // 32 MiB
  unsigned short* uside= (unsigned short*)alloc((size_t)16 * 6 * D_INNER * 2);     // 768 KiB
  unsigned short* ucb  = hid;                  // alias: MLP hidden dead before conv
  float*          sumdt = xpart;               // alias: xpart dead before scan (2 MiB need)
  unsigned short* pA   = (unsigned short*)xz;  // alias: MLP2 bf16 partials; xz written later
  unsigned short* pB   = dtbf;                 // alias: out_proj bf16 partials; dtbf dead after scan

  // --- all weight casts in one dispatch ---
  cvt6<<<21120, 256, 0, stream>>>(w1, w1b, w2, w2b, ipw, ipb, xpw, xpb, dtw, dtb, opw, opb);

  // --- LN1 -> MLP (256^2 MLP1; 256^2 split-K x4 MLP2) -> combine+LN2 ---
  ln_bf16<<<M_ROWS, 256, 0, stream>>>(x, g1, b1, xn);
  gemm256<0><<<dim3(D_INNER / 256, M_ROWS / 256), 512, 0, stream>>>(
      xn, w1b, M_ROWS, D_INNER, D_MODEL, D_MODEL, D_MODEL, D_INNER, bias1, hid,
      nullptr, nullptr, nullptr);
  gemm256<8><<<dim3(D_MODEL / 256, M_ROWS / 256, 4), 512, 0, stream>>>(
      hid, w2b, M_ROWS, D_MODEL, D_INNER / 4, D_INNER, D_INNER, D_MODEL, nullptr, pA,
      nullptr, nullptr, nullptr);
  combine_ln<<<M_ROWS, 256, 0, stream>>>(pA, bias2, x, g2, b2, x2, xn);

  // --- in_proj: u-half with fused conv+silu -> ucb ; z-half -> xz[.,4096:] ---
  gemm256<3><<<dim3(D_INNER / 256, M_ROWS / 256), 512, 0, stream>>>(
      xn, ipb, M_ROWS, D_INNER, D_MODEL, D_MODEL, D_MODEL, D_INNER, nullptr, ucb,
      cw, cb, uside);
  gemm256<2><<<dim3(D_INNER / 256, M_ROWS / 256), 512, 0, stream>>>(
      xn, ipb + (size_t)D_INNER * D_MODEL, M_ROWS, D_INNER, D_MODEL, D_MODEL, D_MODEL,
      2 * D_INNER, nullptr, xz + D_INNER, nullptr, nullptr, nullptr);
  conv_fixup<<<32, 256, 0, stream>>>(uside, cw, cb, ucb);

  // --- x_proj (split-K x8 via blockIdx.z) -> combine ---
  gemm_bt<6><<<dim3(1, M_ROWS / 128, 8), 256, 0, stream>>>(
      ucb, xpb, M_ROWS, 96, 512, D_INNER, D_INNER, 96,
      nullptr, nullptr, xpart);
  xproj_combine<<<M_ROWS * 96 / 256, 256, 0, stream>>>(xpart, dtin, Bmb, Cmb);

  // --- dt_proj + softplus -> bf16 ---
  gemm_bt<4><<<dim3(D_INNER / 128, M_ROWS / 128), 256, 0, stream>>>(
      dtin, dtb, M_ROWS, D_INNER, DT_RANK, DT_RANK, DT_RANK, D_INNER, dtbv, nullptr, dtbf);

  // --- chunk-parallel selective scan (LC=32) -> y (into u-half of xz) ---
  scan_part<<<dim3(D_INNER / 128, NCHUNK, B_SZ), 128, 0, stream>>>(
      dtbf, ucb, Bmb, A_log, Qbuf, sumdt);
  scan_carry<<<B_SZ * D_INNER * 16 / 256, 256, 0, stream>>>(Qbuf, sumdt, A_log);
  scan_final<<<dim3(D_INNER / 128, NCHUNK, B_SZ), 128, 0, stream>>>(
      dtbf, ucb, Bmb, Cmb, xz, A_log, Dvec, Qbuf);

  // --- out_proj (256^2 split-K x4, bf16 partials) + residual -> d_out ---
  gemm256<8><<<dim3(D_MODEL / 256, M_ROWS / 256, 4), 512, 0, stream>>>(
      xz, opb, M_ROWS, D_MODEL, D_INNER / 4, 2 * D_INNER, D_INNER, D_MODEL, nullptr, pB,
      nullptr, nullptr, nullptr);
  splitk_combine_bf<<<M_ROWS * D_MODEL / 1024, 256, 0, stream>>>(pB, x2, (float*)d_out);
}

// Round 17
// 447.295 us; speedup vs baseline: 1.2698x; 1.2698x over previous
//
#include <hip/hip_runtime.h>
#include <cstdint>
#include <cstddef>

// ---------------------------------------------------------------------------
// MambaBlock: x -> x + MLP(LN1(x)) -> (+) mamba(LN2(.))
// B=2 L=2048 d_model=1024 d_inner=4096 d_state=16 d_conv=4 dt_rank=64
// Workspace: ~239 MiB
// R16: REVERT R15 conv-fusion (568us: split in_proj halves ran at 116us /
//      MfmaUtil 11% -- template graft perturbed codegen; fusion falsified).
//      This is the R14 measured-best configuration (447.97us).
// ---------------------------------------------------------------------------

namespace {
constexpr int D_MODEL = 1024;
constexpr int D_INNER = 4096;
constexpr int D_STATE = 16;
constexpr int DT_RANK = 64;
constexpr int B_SZ    = 2;
constexpr int L_SEQ   = 2048;
constexpr int M_ROWS  = B_SZ * L_SEQ;   // 4096 token rows
constexpr int LC      = 32;             // scan chunk length
constexpr int NCHUNK  = L_SEQ / LC;     // 64
}

typedef __bf16 bf16x8_t __attribute__((ext_vector_type(8)));
typedef float  f32x4    __attribute__((ext_vector_type(4)));
typedef unsigned short us8 __attribute__((ext_vector_type(8)));

__device__ __forceinline__ unsigned short f2bf(float f) {
  union { float f; unsigned int u; } v; v.f = f;
  unsigned int r = (v.u + 0x7fffu + ((v.u >> 16) & 1u)) >> 16;
  return (unsigned short)r;
}
__device__ __forceinline__ float bf2f(unsigned short s) {
  union { unsigned int u; float f; } v; v.u = ((unsigned int)s) << 16;
  return v.f;
}

// branchless softplus on HW trans pipe: max(v,0) + ln2*log2(1+exp2(-|v|*log2e))
__device__ __forceinline__ float softplus_fast(float v) {
  const float e = __builtin_amdgcn_exp2f(-fabsf(v) * 1.44269504088896f);
  return fmaxf(v, 0.f) + 0.693147180559945f * __builtin_amdgcn_logf(1.f + e);
}

// async global->LDS, 16B per lane. LDS dest must be wave-uniform base;
// HW writes base + lane*16.
__device__ __forceinline__ void gload16(const void* g, void* l) {
  __builtin_amdgcn_global_load_lds(
      (const __attribute__((address_space(1))) unsigned int*)g,
      (__attribute__((address_space(3))) unsigned int*)l, 16, 0, 0);
}

// ---------------------------------------------------------------------------
// fused f32 -> bf16 cast for all 6 weight tensors (1024 elems / block)
// ---------------------------------------------------------------------------
__global__ __launch_bounds__(256)
void cvt6(const float* __restrict__ s0, unsigned short* __restrict__ d0,
          const float* __restrict__ s1, unsigned short* __restrict__ d1,
          const float* __restrict__ s2, unsigned short* __restrict__ d2,
          const float* __restrict__ s3, unsigned short* __restrict__ d3,
          const float* __restrict__ s4, unsigned short* __restrict__ d4,
          const float* __restrict__ s5, unsigned short* __restrict__ d5) {
  int blk = blockIdx.x;
  const float* s; unsigned short* d;
  if (blk < 4096)                  { s = s0; d = d0; }
  else if ((blk -= 4096) < 4096)   { s = s1; d = d1; }
  else if ((blk -= 4096) < 8192)   { s = s2; d = d2; }
  else if ((blk -= 8192) < 384)    { s = s3; d = d3; }
  else if ((blk -= 384) < 256)     { s = s4; d = d4; }
  else { blk -= 256;                 s = s5; d = d5; }
  const int i = blk * 1024 + threadIdx.x * 4;
  float4 v = *(const float4*)(s + i);
  ushort4 o; o.x = f2bf(v.x); o.y = f2bf(v.y); o.z = f2bf(v.z); o.w = f2bf(v.w);
  *(ushort4*)(d + i) = o;
}

// ---------------------------------------------------------------------------
// LayerNorm over D_MODEL=1024; one block (256 thr) per row; bf16 out
// ---------------------------------------------------------------------------
__global__ __launch_bounds__(256) void ln_bf16(const float* __restrict__ x,
                                               const float* __restrict__ g,
                                               const float* __restrict__ b,
                                               unsigned short* __restrict__ out) {
  const int row = blockIdx.x;
  const int tid = threadIdx.x;
  const float4 v = *(const float4*)(x + (size_t)row * D_MODEL + tid * 4);
  float s  = v.x + v.y + v.z + v.w;
  float s2 = v.x*v.x + v.y*v.y + v.z*v.z + v.w*v.w;
#pragma unroll
  for (int o = 32; o >= 1; o >>= 1) { s += __shfl_xor(s, o); s2 += __shfl_xor(s2, o); }
  __shared__ float red[8];
  if ((tid & 63) == 0) { red[(tid >> 6) * 2] = s; red[(tid >> 6) * 2 + 1] = s2; }
  __syncthreads();
  s  = red[0] + red[2] + red[4] + red[6];
  s2 = red[1] + red[3] + red[5] + red[7];
  const float mu  = s * (1.f / D_MODEL);
  const float var = s2 * (1.f / D_MODEL) - mu * mu;
  const float rstd = rsqrtf(var + 1e-5f);
  const float4 gv = *(const float4*)(g + tid * 4);
  const float4 bv = *(const float4*)(b + tid * 4);
  ushort4 o;
  o.x = f2bf((v.x - mu) * rstd * gv.x + bv.x);
  o.y = f2bf((v.y - mu) * rstd * gv.y + bv.y);
  o.z = f2bf((v.z - mu) * rstd * gv.z + bv.z);
  o.w = f2bf((v.w - mu) * rstd * gv.w + bv.w);
  *(ushort4*)(out + (size_t)row * D_MODEL + tid * 4) = o;
}

// ---------------------------------------------------------------------------
// fused: x2 = sum4(MLP2 bf16 partials) + bias2 + x ; xn = LN(x2) bf16
// ---------------------------------------------------------------------------
__global__ __launch_bounds__(256)
void combine_ln(const unsigned short* __restrict__ part, const float* __restrict__ bias,
                const float* __restrict__ res, const float* __restrict__ g,
                const float* __restrict__ b, float* __restrict__ x2out,
                unsigned short* __restrict__ xnout) {
  const int row = blockIdx.x;
  const int tid = threadIdx.x;
  const size_t i4 = (size_t)row * D_MODEL + tid * 4;
  constexpr size_t S = (size_t)M_ROWS * D_MODEL;
  float a0 = 0.f, a1 = 0.f, a2 = 0.f, a3 = 0.f;
#pragma unroll
  for (int z = 0; z < 4; ++z) {
    const ushort4 p = *(const ushort4*)(part + z * S + i4);
    a0 += bf2f(p.x); a1 += bf2f(p.y); a2 += bf2f(p.z); a3 += bf2f(p.w);
  }
  const float4 bv = *(const float4*)(bias + tid * 4);
  const float4 rv = *(const float4*)(res + i4);
  float4 v;
  v.x = a0 + bv.x + rv.x;
  v.y = a1 + bv.y + rv.y;
  v.z = a2 + bv.z + rv.z;
  v.w = a3 + bv.w + rv.w;
  *(float4*)(x2out + i4) = v;
  float s  = v.x + v.y + v.z + v.w;
  float s2 = v.x*v.x + v.y*v.y + v.z*v.z + v.w*v.w;
#pragma unroll
  for (int o = 32; o >= 1; o >>= 1) { s += __shfl_xor(s, o); s2 += __shfl_xor(s2, o); }
  __shared__ float red[8];
  if ((tid & 63) == 0) { red[(tid >> 6) * 2] = s; red[(tid >> 6) * 2 + 1] = s2; }
  __syncthreads();
  s  = red[0] + red[2] + red[4] + red[6];
  s2 = red[1] + red[3] + red[5] + red[7];
  const float mu  = s * (1.f / D_MODEL);
  const float var = s2 * (1.f / D_MODEL) - mu * mu;
  const float rstd = rsqrtf(var + 1e-5f);
  const float4 gv = *(const float4*)(g + tid * 4);
  const float4 b2 = *(const float4*)(b + tid * 4);
  ushort4 o;
  o.x = f2bf((v.x - mu) * rstd * gv.x + b2.x);
  o.y = f2bf((v.y - mu) * rstd * gv.y + b2.y);
  o.z = f2bf((v.z - mu) * rstd * gv.z + b2.z);
  o.w = f2bf((v.w - mu) * rstd * gv.w + b2.w);
  *(ushort4*)(xnout + i4) = o;
}

// ---------------------------------------------------------------------------
// 256x256-tile 8-wave bf16 GEMM, BK=64, read-once fragments + LDS-staged
// coalesced epilogue. (R14 measured-best structure.)
// EPI: 0 silu(v+bias)->bf16 | 2 v->bf16 (non-temporal)
//      8 v->bf16 partial (split-K via blockIdx.z, chunk K elems at z*K)
// M%256==0, N%256==0, K%64==0.
// ---------------------------------------------------------------------------
template<int EPI>
__global__ __launch_bounds__(512, 1)
void gemm256(const unsigned short* __restrict__ A, const unsigned short* __restrict__ W,
             int M, int N, int K, int lda, int ldw,
             const float* __restrict__ bias, void* __restrict__ out0) {
  if constexpr (EPI == 8) {
    const size_t koff = (size_t)blockIdx.z * K;
    A += koff; W += koff;
    out0 = (void*)((unsigned short*)out0 + (size_t)blockIdx.z * M * N);
  }
  __shared__ unsigned short smem[65536];  // As[2]:0..32767, Bs[2]:32768..65535
  const int tid  = threadIdx.x;
  const int w    = tid >> 6;
  const int lane = tid & 63;
  const int wr = w >> 2;            // 0..1 : wave row  (128 rows of C)
  const int wc = w & 3;             // 0..3 : wave col  (64 cols of C)
  const int fr = lane & 15;
  const int fq = lane >> 4;         // 0..3

  // XCD-aware chunked swizzle (nwg % 8 == 0)
  const int gx = gridDim.x, gy = gridDim.y;
  const int nwg = gx * gy;
  const int id  = blockIdx.y * gx + blockIdx.x;
  const int wid = (id & 7) * (nwg >> 3) + (id >> 3);
  const int n0 = (wid / gy) * 256;
  const int m0 = (wid % gy) * 256;

  // staging indices: 512 threads; line = 64 rows x 64 k (8 KB); 4 lines/operand
  const int srow  = tid >> 3;                       // 0..63 row within line
  const int skelem = ((tid & 7) ^ (srow & 7)) * 8;  // pre-swizzled k-offset

  // read-side swizzled slot offsets (elements), per-lane constant
  int aslot[2];
#pragma unroll
  for (int ks = 0; ks < 2; ++ks) aslot[ks] = ((ks * 4 + fq) ^ (fr & 7)) * 8;

  f32x4 acc[8][4];
#pragma unroll
  for (int m = 0; m < 8; ++m)
#pragma unroll
    for (int n = 0; n < 4; ++n) acc[m][n] = f32x4{0.f, 0.f, 0.f, 0.f};

  const int NT = K >> 6;

  auto STAGE_HALF = [&](int half, int tn, unsigned short* Ad, unsigned short* Bd) {
    const int k0 = tn * 64;
    if (half < 2) {
#pragma unroll
      for (int li = 0; li < 2; ++li) {
        const int l = half * 2 + li;
        gload16(A + (size_t)(m0 + l * 64 + srow) * lda + k0 + skelem,
                Ad + (l * 64 + w * 8) * 64);
      }
    } else {
#pragma unroll
      for (int li = 0; li < 2; ++li) {
        const int l = (half - 2) * 2 + li;
        gload16(W + (size_t)(n0 + l * 64 + srow) * ldw + k0 + skelem,
                Bd + (l * 64 + w * 8) * 64);
      }
    }
  };

  // prologue: stage tile 0 -> buf 0
#pragma unroll
  for (int h = 0; h < 4; ++h) STAGE_HALF(h, 0, smem, smem + 32768);
  asm volatile("s_waitcnt vmcnt(0)" ::: "memory");
  __builtin_amdgcn_s_barrier();

  for (int t = 0; t < NT; ++t) {
    const int cur = t & 1;
    const unsigned short* Ab = smem + cur * 16384;
    const unsigned short* Bb = smem + 32768 + cur * 16384;
    unsigned short* Adn = smem + (cur ^ 1) * 16384;
    unsigned short* Bdn = smem + 32768 + (cur ^ 1) * 16384;
    const bool more = (t + 1 < NT);

    bf16x8_t af[4][2], bflo[2][2], bfhi[2][2];

    // ---- phase 0: quadrant (0,0). read af_lo + bf_lo; stage halves 0,1
#pragma unroll
    for (int mfi = 0; mfi < 4; ++mfi)
#pragma unroll
      for (int ks = 0; ks < 2; ++ks)
        af[mfi][ks] = *(const bf16x8_t*)
            &Ab[(wr * 128 + mfi * 16 + fr) * 64 + aslot[ks]];
#pragma unroll
    for (int nfi = 0; nfi < 2; ++nfi)
#pragma unroll
      for (int ks = 0; ks < 2; ++ks)
        bflo[nfi][ks] = *(const bf16x8_t*)
            &Bb[(wc * 64 + nfi * 16 + fr) * 64 + aslot[ks]];
    if (more) { STAGE_HALF(0, t + 1, Adn, Bdn); STAGE_HALF(1, t + 1, Adn, Bdn); }
    asm volatile("s_waitcnt lgkmcnt(0)" ::: "memory");
    __builtin_amdgcn_s_barrier();
    __builtin_amdgcn_s_setprio(1);
#pragma unroll
    for (int mfi = 0; mfi < 4; ++mfi)
#pragma unroll
      for (int nfi = 0; nfi < 2; ++nfi)
#pragma unroll
        for (int ks = 0; ks < 2; ++ks)
          acc[mfi][nfi] = __builtin_amdgcn_mfma_f32_16x16x32_bf16(
              af[mfi][ks], bflo[nfi][ks], acc[mfi][nfi], 0, 0, 0);
    __builtin_amdgcn_s_setprio(0);

    // ---- phase 1: quadrant (0,1). read bf_hi; stage halves 2,3
#pragma unroll
    for (int nfi = 0; nfi < 2; ++nfi)
#pragma unroll
      for (int ks = 0; ks < 2; ++ks)
        bfhi[nfi][ks] = *(const bf16x8_t*)
            &Bb[(wc * 64 + (2 + nfi) * 16 + fr) * 64 + aslot[ks]];
    if (more) { STAGE_HALF(2, t + 1, Adn, Bdn); STAGE_HALF(3, t + 1, Adn, Bdn); }
    asm volatile("s_waitcnt lgkmcnt(0)" ::: "memory");
    __builtin_amdgcn_s_barrier();
    __builtin_amdgcn_s_setprio(1);
#pragma unroll
    for (int mfi = 0; mfi < 4; ++mfi)
#pragma unroll
      for (int nfi = 0; nfi < 2; ++nfi)
#pragma unroll
        for (int ks = 0; ks < 2; ++ks)
          acc[mfi][2 + nfi] = __builtin_amdgcn_mfma_f32_16x16x32_bf16(
              af[mfi][ks], bfhi[nfi][ks], acc[mfi][2 + nfi], 0, 0, 0);
    __builtin_amdgcn_s_setprio(0);

    // ---- phase 2: quadrant (1,0). read af_hi into af regs (time-share)
#pragma unroll
    for (int mfi = 0; mfi < 4; ++mfi)
#pragma unroll
      for (int ks = 0; ks < 2; ++ks)
        af[mfi][ks] = *(const bf16x8_t*)
            &Ab[(wr * 128 + (4 + mfi) * 16 + fr) * 64 + aslot[ks]];
    asm volatile("s_waitcnt lgkmcnt(0)" ::: "memory");
    __builtin_amdgcn_s_barrier();
    __builtin_amdgcn_s_setprio(1);
#pragma unroll
    for (int mfi = 0; mfi < 4; ++mfi)
#pragma unroll
      for (int nfi = 0; nfi < 2; ++nfi)
#pragma unroll
        for (int ks = 0; ks < 2; ++ks)
          acc[4 + mfi][nfi] = __builtin_amdgcn_mfma_f32_16x16x32_bf16(
              af[mfi][ks], bflo[nfi][ks], acc[4 + mfi][nfi], 0, 0, 0);
    __builtin_amdgcn_s_setprio(0);

    // ---- phase 3: quadrant (1,1). no ds_reads.
    __builtin_amdgcn_s_setprio(1);
#pragma unroll
    for (int mfi = 0; mfi < 4; ++mfi)
#pragma unroll
      for (int nfi = 0; nfi < 2; ++nfi)
#pragma unroll
        for (int ks = 0; ks < 2; ++ks)
          acc[4 + mfi][2 + nfi] = __builtin_amdgcn_mfma_f32_16x16x32_bf16(
              af[mfi][ks], bfhi[nfi][ks], acc[4 + mfi][2 + nfi], 0, 0, 0);
    __builtin_amdgcn_s_setprio(0);

    // K-tile boundary: drain next tile's staging, release both buffers
    asm volatile("s_waitcnt vmcnt(0)" ::: "memory");
    __builtin_amdgcn_s_barrier();
  }

  // ---- LDS-staged coalesced epilogue: smem reused as C[256][256] bf16 ----
  unsigned short* Cs = smem;
#pragma unroll
  for (int mf = 0; mf < 8; ++mf)
#pragma unroll
    for (int nf = 0; nf < 4; ++nf)
#pragma unroll
      for (int j = 0; j < 4; ++j) {
        const int row = wr * 128 + mf * 16 + fq * 4 + j;
        const int col = wc * 64 + nf * 16 + fr;
        float v = acc[mf][nf][j];
        if constexpr (EPI == 0) {
          v += bias[n0 + col];
          v = v / (1.f + __expf(-v));
        }
        Cs[row * 256 + ((((col >> 3) ^ (row & 7)) << 3) | (col & 7))] = f2bf(v);
      }
  __syncthreads();
  unsigned short* outp = (unsigned short*)out0;
  const int trow = tid >> 5;        // 0..15
  const int tg   = tid & 31;        // col group
#pragma unroll
  for (int i = 0; i < 16; ++i) {
    const int row = i * 16 + trow;
    const us8 vv = *(const us8*)&Cs[row * 256 + ((tg ^ (row & 7)) << 3)];
    unsigned short* dst = &outp[(size_t)(m0 + row) * N + n0 + tg * 8];
    if constexpr (EPI == 2) __builtin_nontemporal_store(vv, (us8*)dst);
    else                    *(us8*)dst = vv;
  }
}

// ---------------------------------------------------------------------------
// 128x128 2-phase bf16 GEMM (small shapes) + LDS-staged epilogue for bf16.
// EPI: 4 softplus(v+bias)->bf16 | 6 v->f32 partial (split-K via blockIdx.z)
// ---------------------------------------------------------------------------
template<int EPI>
__global__ __launch_bounds__(256)
void gemm_bt(const unsigned short* __restrict__ A, const unsigned short* __restrict__ W,
             int M, int N, int K, int lda, int ldw, int ldc,
             const float* __restrict__ bias, const float* __restrict__ res,
             void* __restrict__ out0) {
  if constexpr (EPI == 6) {
    const size_t koff = (size_t)blockIdx.z * K;
    A += koff; W += koff;
    out0 = (void*)((float*)out0 + (size_t)blockIdx.z * M * ldc);
  }
  const int gx = gridDim.x, gy = gridDim.y;
  const int nwg = gx * gy;
  const int id  = blockIdx.y * gx + blockIdx.x;
  const int wid = (nwg >= 8) ? ((id & 7) * (nwg >> 3) + (id >> 3)) : id;
  const int n0 = (wid / gy) * 128;
  const int m0 = (wid % gy) * 128;

  __shared__ unsigned short smem[16384];  // As[2]:0..8191, Bs[2]:8192..16383
  const int tid  = threadIdx.x;
  const int w    = tid >> 6;
  const int lane = tid & 63;
  const int wm = (w >> 1) * 64;
  const int wn = (w & 1) * 64;
  const int lrow = lane >> 2;
  const int lkb  = (lane & 3) * 8;
  const int fr   = lane & 15;
  const int fq   = lane >> 4;

  f32x4 acc[4][4];
#pragma unroll
  for (int m = 0; m < 4; ++m)
#pragma unroll
    for (int n = 0; n < 4; ++n) acc[m][n] = f32x4{0.f, 0.f, 0.f, 0.f};

  const int ar0 = m0 + (w * 2 + 0) * 16 + lrow;
  const int ar1 = m0 + (w * 2 + 1) * 16 + lrow;
  int br0 = n0 + (w * 2 + 0) * 16 + lrow; if (br0 > N - 1) br0 = N - 1;
  int br1 = n0 + (w * 2 + 1) * 16 + lrow; if (br1 > N - 1) br1 = N - 1;

  const int nk = K >> 5;
  auto STAGE = [&](int buf, int kt) {
    const int k0 = kt * 32;
    gload16(A + (size_t)ar0 * lda + k0 + lkb, smem + buf * 4096 + (w * 2 + 0) * 512);
    gload16(A + (size_t)ar1 * lda + k0 + lkb, smem + buf * 4096 + (w * 2 + 1) * 512);
    gload16(W + (size_t)br0 * ldw + k0 + lkb, smem + 8192 + buf * 4096 + (w * 2 + 0) * 512);
    gload16(W + (size_t)br1 * ldw + k0 + lkb, smem + 8192 + buf * 4096 + (w * 2 + 1) * 512);
  };
  STAGE(0, 0);
  if (nk > 1) STAGE(1, 1);

  for (int kt = 0; kt < nk; ++kt) {
    const int cur = kt & 1;
    if (kt + 1 < nk) asm volatile("s_waitcnt vmcnt(4)" ::: "memory");
    else             asm volatile("s_waitcnt vmcnt(0)" ::: "memory");
    __builtin_amdgcn_s_barrier();
    const unsigned short* Ac = smem + cur * 4096;
    const unsigned short* Bc = smem + 8192 + cur * 4096;
    bf16x8_t af[4], bf[4];
#pragma unroll
    for (int m = 0; m < 4; ++m) af[m] = *(const bf16x8_t*)&Ac[(wm + m * 16 + fr) * 32 + fq * 8];
#pragma unroll
    for (int n = 0; n < 4; ++n) bf[n] = *(const bf16x8_t*)&Bc[(wn + n * 16 + fr) * 32 + fq * 8];
    __builtin_amdgcn_s_setprio(1);
#pragma unroll
    for (int m = 0; m < 4; ++m)
#pragma unroll
      for (int n = 0; n < 4; ++n)
        acc[m][n] = __builtin_amdgcn_mfma_f32_16x16x32_bf16(af[m], bf[n], acc[m][n], 0, 0, 0);
    __builtin_amdgcn_s_setprio(0);
    asm volatile("s_waitcnt lgkmcnt(0)" ::: "memory");
    __builtin_amdgcn_s_barrier();
    if (kt + 2 < nk) STAGE(cur, kt + 2);
  }

  if constexpr (EPI == 6) {
#pragma unroll
    for (int m = 0; m < 4; ++m)
#pragma unroll
      for (int n = 0; n < 4; ++n)
#pragma unroll
        for (int j = 0; j < 4; ++j) {
          const int r = m0 + wm + m * 16 + fq * 4 + j;
          const int c = n0 + wn + n * 16 + fr;
          if (c >= N) continue;
          ((float*)out0)[(size_t)r * ldc + c] = acc[m][n][j];
        }
  } else {
    // LDS-staged coalesced epilogue: smem reused as C[128][128] bf16
    unsigned short* Cs = smem;
#pragma unroll
    for (int m = 0; m < 4; ++m)
#pragma unroll
      for (int n = 0; n < 4; ++n)
#pragma unroll
        for (int j = 0; j < 4; ++j) {
          const int row = wm + m * 16 + fq * 4 + j;
          const int col = wn + n * 16 + fr;
          float v = acc[m][n][j];
          if constexpr (EPI == 4) v = softplus_fast(v + bias[n0 + col]);
          Cs[row * 128 + ((((col >> 3) ^ (row & 7)) << 3) | (col & 7))] = f2bf(v);
        }
    __syncthreads();
    unsigned short* outp = (unsigned short*)out0;
    const int trow = tid >> 4;        // 0..15
    const int tg   = tid & 15;        // col group
#pragma unroll
    for (int i = 0; i < 8; ++i) {
      const int row = i * 16 + trow;
      const us8 vv = *(const us8*)&Cs[row * 128 + ((tg ^ (row & 7)) << 3)];
      *(us8*)&outp[(size_t)(m0 + row) * ldc + n0 + tg * 8] = vv;
    }
  }
}

// ---------------------------------------------------------------------------
// split-K x4 combiner (bf16 partials): out = sum4 + res  (out_proj epilogue)
// ---------------------------------------------------------------------------
__global__ __launch_bounds__(256)
void splitk_combine_bf(const unsigned short* __restrict__ part,
                       const float* __restrict__ res, float* __restrict__ out) {
  const size_t i4 = ((size_t)blockIdx.x * 256 + threadIdx.x) * 4;
  constexpr size_t S = (size_t)M_ROWS * D_MODEL;
  float a0 = 0.f, a1 = 0.f, a2 = 0.f, a3 = 0.f;
#pragma unroll
  for (int z = 0; z < 4; ++z) {
    const ushort4 p = *(const ushort4*)(part + z * S + i4);
    a0 += bf2f(p.x); a1 += bf2f(p.y); a2 += bf2f(p.z); a3 += bf2f(p.w);
  }
  const float4 r = *(const float4*)(res + i4);
  *(float4*)(out + i4) = float4{a0 + r.x, a1 + r.y, a2 + r.z, a3 + r.w};
}

// ---------------------------------------------------------------------------
// causal depthwise conv1d (k=4) + silu, 8 channels/thread, vectorized loads
// reads u-part of xz (bf16), writes bf16
// ---------------------------------------------------------------------------
__global__ __launch_bounds__(256)
void conv_silu_k(const unsigned short* __restrict__ xz, const float* __restrict__ cw,
                 const float* __restrict__ cb, unsigned short* __restrict__ uc) {
  const size_t idx = (size_t)blockIdx.x * 256 + threadIdx.x;  // over M_ROWS*512
  const int dg  = (int)(idx & 511) * 8;     // channel group base
  const int row = (int)(idx >> 9);
  const int l   = row & (L_SEQ - 1);
  const unsigned short* up = xz + (size_t)row * (2 * D_INNER) + dg;
  us8 t0 = {0,0,0,0,0,0,0,0}, t1 = {0,0,0,0,0,0,0,0}, t2 = {0,0,0,0,0,0,0,0};
  const us8 t3 = *(const us8*)(up);
  if (l >= 1) t2 = *(const us8*)(up - (ptrdiff_t)1 * 2 * D_INNER);
  if (l >= 2) t1 = *(const us8*)(up - (ptrdiff_t)2 * 2 * D_INNER);
  if (l >= 3) t0 = *(const us8*)(up - (ptrdiff_t)3 * 2 * D_INNER);
  us8 o;
#pragma unroll
  for (int j = 0; j < 8; ++j) {
    const float4 w4 = *(const float4*)(cw + (dg + j) * 4);
    float acc = cb[dg + j];
    acc += bf2f(t0[j]) * w4.x;
    acc += bf2f(t1[j]) * w4.y;
    acc += bf2f(t2[j]) * w4.z;
    acc += bf2f(t3[j]) * w4.w;
    o[j] = f2bf(acc / (1.f + __expf(-acc)));
  }
  *(us8*)(uc + (size_t)row * D_INNER + dg) = o;
}

// ---------------------------------------------------------------------------
// split-K combiner for x_proj: part[8][4096][96] -> dt_in(bf16), Bm, Cm (f32)
// ---------------------------------------------------------------------------
__global__ __launch_bounds__(256)
void xproj_combine(const float* __restrict__ part, unsigned short* __restrict__ dtin,
                   float* __restrict__ Bm, float* __restrict__ Cm) {
  const int idx = blockIdx.x * 256 + threadIdx.x;  // 4096*96
  const int r = idx / 96, c = idx - r * 96;
  constexpr size_t S = (size_t)M_ROWS * 96;
  float v = 0.f;
#pragma unroll
  for (int z = 0; z < 8; ++z) v += part[idx + z * S];
  if (c < DT_RANK)            dtin[(size_t)r * DT_RANK + c] = f2bf(v);
  else if (c < DT_RANK + 16)  Bm[(size_t)r * 16 + (c - DT_RANK)] = v;
  else                        Cm[(size_t)r * 16 + (c - DT_RANK - 16)] = v;
}

// ---------------------------------------------------------------------------
// Chunk-parallel selective scan, LC=32 (diagonal dA => chunk composes as
// h = P*h_in + Q, P = exp(A*sum_dt)). Thread owns one channel d: h[16] regs.
// ---------------------------------------------------------------------------
__global__ __launch_bounds__(128)
void scan_part(const unsigned short* __restrict__ dt, const unsigned short* __restrict__ uc,
               const float* __restrict__ Bm, const float* __restrict__ A_log,
               float* __restrict__ Q, float* __restrict__ sumdt) {
  __shared__ float sB[LC][D_STATE];
  const int lt = threadIdx.x;
  const int d  = blockIdx.x * 128 + lt;
  const int c  = blockIdx.y;
  const int b  = blockIdx.z;
  const size_t rowbase = (size_t)b * L_SEQ + (size_t)c * LC;
  ((float4*)&sB[0][0])[lt] = ((const float4*)(Bm + rowbase * D_STATE))[lt];
  float Ap[D_STATE];
#pragma unroll
  for (int s = 0; s < D_STATE; ++s)
    Ap[s] = -__expf(A_log[d * D_STATE + s]) * 1.44269504088896f;
  float h[D_STATE];
#pragma unroll
  for (int s = 0; s < D_STATE; ++s) h[s] = 0.f;
  float sdt = 0.f;
  __syncthreads();
  for (int t = 0; t < LC; ++t) {
    const size_t row = rowbase + t;
    const float dtv = bf2f(dt[row * D_INNER + d]);
    const float uv  = bf2f(uc[row * D_INNER + d]);
    sdt += dtv;
    const float du = dtv * uv;
    const float4* bp = (const float4*)&sB[t][0];
    const float4 b0 = bp[0], b1 = bp[1], b2 = bp[2], b3 = bp[3];
    const float Bv[16] = {b0.x,b0.y,b0.z,b0.w, b1.x,b1.y,b1.z,b1.w,
                          b2.x,b2.y,b2.z,b2.w, b3.x,b3.y,b3.z,b3.w};
#pragma unroll
    for (int s = 0; s < D_STATE; ++s) {
      const float dA = __builtin_amdgcn_exp2f(dtv * Ap[s]);
      h[s] = fmaf(dA, h[s], du * Bv[s]);
    }
  }
  float* q = Q + ((((size_t)b * NCHUNK + c) * D_INNER + d) << 4);
#pragma unroll
  for (int s = 0; s < D_STATE; s += 4)
    *(float4*)(q + s) = float4{h[s], h[s+1], h[s+2], h[s+3]};
  sumdt[((size_t)b * NCHUNK + c) * D_INNER + d] = sdt;
}

__global__ __launch_bounds__(256)
void scan_carry(float* __restrict__ Q, const float* __restrict__ sumdt,
                const float* __restrict__ A_log) {
  const int idx = blockIdx.x * 256 + threadIdx.x;   // (b,d,s)
  const int s = idx & 15;
  const int d = (idx >> 4) & (D_INNER - 1);
  const int b = idx >> 16;
  const float Ap = -__expf(A_log[d * D_STATE + s]) * 1.44269504088896f;
  float h = 0.f;
  for (int c = 0; c < NCHUNK; ++c) {
    const size_t base = ((size_t)b * NCHUNK + c) * D_INNER;
    const size_t qoff = ((base + d) << 4) + s;
    const float q = Q[qoff];
    const float P = __builtin_amdgcn_exp2f(sumdt[base + d] * Ap);
    Q[qoff] = h;
    h = fmaf(P, h, q);
  }
}

__global__ __launch_bounds__(128)
void scan_final(const unsigned short* __restrict__ dt, const unsigned short* __restrict__ uc,
                const float* __restrict__ Bm, const float* __restrict__ Cm,
                unsigned short* __restrict__ xz, const float* __restrict__ A_log,
                const float* __restrict__ Dvec, const float* __restrict__ Hin) {
  __shared__ float sB[LC][D_STATE];
  __shared__ float sC[LC][D_STATE];
  const int lt = threadIdx.x;
  const int d  = blockIdx.x * 128 + lt;
  const int c  = blockIdx.y;
  const int b  = blockIdx.z;
  const size_t rowbase = (size_t)b * L_SEQ + (size_t)c * LC;
  ((float4*)&sB[0][0])[lt] = ((const float4*)(Bm + rowbase * D_STATE))[lt];
  ((float4*)&sC[0][0])[lt] = ((const float4*)(Cm + rowbase * D_STATE))[lt];
  float Ap[D_STATE];
#pragma unroll
  for (int s = 0; s < D_STATE; ++s)
    Ap[s] = -__expf(A_log[d * D_STATE + s]) * 1.44269504088896f;
  float h[D_STATE];
  const float* hin = Hin + ((((size_t)b * NCHUNK + c) * D_INNER + d) << 4);
#pragma unroll
  for (int s = 0; s < D_STATE; s += 4) {
    const float4 hv = *(const float4*)(hin + s);
    h[s] = hv.x; h[s+1] = hv.y; h[s+2] = hv.z; h[s+3] = hv.w;
  }
  const float Dv = Dvec[d];
  __syncthreads();
  for (int t = 0; t < LC; ++t) {
    const size_t row = rowbase + t;
    const float dtv = bf2f(dt[row * D_INNER + d]);
    const float uv  = bf2f(uc[row * D_INNER + d]);
    const float zv  = bf2f(xz[row * (2 * D_INNER) + D_INNER + d]);
    const float du = dtv * uv;
    const float4* bp = (const float4*)&sB[t][0];
    const float4 b0 = bp[0], b1 = bp[1], b2 = bp[2], b3 = bp[3];
    const float Bv[16] = {b0.x,b0.y,b0.z,b0.w, b1.x,b1.y,b1.z,b1.w,
                          b2.x,b2.y,b2.z,b2.w, b3.x,b3.y,b3.z,b3.w};
    const float4* cp = (const float4*)&sC[t][0];
    const float4 c0 = cp[0], c1 = cp[1], c2 = cp[2], c3 = cp[3];
    const float Cv[16] = {c0.x,c0.y,c0.z,c0.w, c1.x,c1.y,c1.z,c1.w,
                          c2.x,c2.y,c2.z,c2.w, c3.x,c3.y,c3.z,c3.w};
    float y0 = 0.f, y1 = 0.f;
#pragma unroll
    for (int s = 0; s < D_STATE; s += 2) {
      const float dA0 = __builtin_amdgcn_exp2f(dtv * Ap[s]);
      const float dA1 = __builtin_amdgcn_exp2f(dtv * Ap[s+1]);
      h[s]   = fmaf(dA0, h[s],   du * Bv[s]);
      h[s+1] = fmaf(dA1, h[s+1], du * Bv[s+1]);
      y0 = fmaf(h[s],   Cv[s],   y0);
      y1 = fmaf(h[s+1], Cv[s+1], y1);
    }
    const float yo = (y0 + y1 + uv * Dv) * (zv / (1.f + __expf(-zv)));
    xz[row * (2 * D_INNER) + d] = f2bf(yo);
  }
}

// ---------------------------------------------------------------------------
extern "C" void kernel_launch(void* const* d_in, const int* in_sizes, int n_in,
                              void* d_out, int out_size, void* d_ws, size_t ws_size,
                              hipStream_t stream) {
  (void)in_sizes; (void)n_in; (void)out_size; (void)ws_size;
  const float* x     = (const float*)d_in[0];
  const float* g1    = (const float*)d_in[1];
  const float* b1    = (const float*)d_in[2];
  const float* g2    = (const float*)d_in[3];
  const float* b2    = (const float*)d_in[4];
  const float* w1    = (const float*)d_in[5];
  const float* bias1 = (const float*)d_in[6];
  const float* w2    = (const float*)d_in[7];
  const float* bias2 = (const float*)d_in[8];
  const float* ipw   = (const float*)d_in[9];
  const float* cw    = (const float*)d_in[10];
  const float* cb    = (const float*)d_in[11];
  const float* xpw   = (const float*)d_in[12];
  const float* dtw   = (const float*)d_in[13];
  const float* dtbv  = (const float*)d_in[14];
  const float* A_log = (const float*)d_in[15];
  const float* Dvec  = (const float*)d_in[16];
  const float* opw   = (const float*)d_in[17];

  char* ws = (char*)d_ws;
  size_t off = 0;
  auto alloc = [&](size_t bytes) { void* p = ws + off; off = (off + bytes + 255) & ~(size_t)255; return p; };

  // weights (41.25 MiB)
  unsigned short* w1b  = (unsigned short*)alloc((size_t)D_INNER * D_MODEL * 2);
  unsigned short* w2b  = (unsigned short*)alloc((size_t)D_MODEL * D_INNER * 2);
  unsigned short* ipb  = (unsigned short*)alloc((size_t)2 * D_INNER * D_MODEL * 2);
  unsigned short* xpb  = (unsigned short*)alloc((size_t)96 * D_INNER * 2);
  unsigned short* dtb  = (unsigned short*)alloc((size_t)D_INNER * DT_RANK * 2);
  unsigned short* opb  = (unsigned short*)alloc((size_t)D_MODEL * D_INNER * 2);
  // activations
  unsigned short* xn   = (unsigned short*)alloc((size_t)M_ROWS * D_MODEL * 2);     // 8 MiB
  unsigned short* hid  = (unsigned short*)alloc((size_t)M_ROWS * D_INNER * 2);     // 32 MiB
  float*          x2   = (float*)alloc((size_t)M_ROWS * D_MODEL * 4);              // 16 MiB
  unsigned short* xz   = (unsigned short*)alloc((size_t)M_ROWS * 2 * D_INNER * 2); // 64 MiB
  unsigned short* dtbf = (unsigned short*)alloc((size_t)M_ROWS * D_INNER * 2);     // 32 MiB
  unsigned short* dtin = (unsigned short*)alloc((size_t)M_ROWS * DT_RANK * 2);
  float*          Bmb  = (float*)alloc((size_t)M_ROWS * 16 * 4);
  float*          Cmb  = (float*)alloc((size_t)M_ROWS * 16 * 4);
  float*          xpart= (float*)alloc((size_t)8 * M_ROWS * 96 * 4);               // 12.6 MiB
  float*          Qbuf = (float*)alloc((size_t)B_SZ * NCHUNK * D_INNER * 16 * 4);  // 32 MiB
  unsigned short* ucb  = hid;                  // alias: MLP hidden dead before conv
  float*          sumdt = xpart;               // alias: xpart dead before scan (2 MiB need)
  unsigned short* pA   = (unsigned short*)xz;  // alias: MLP2 bf16 partials; xz written later
  unsigned short* pB   = dtbf;                 // alias: out_proj bf16 partials; dtbf dead after scan

  // --- all weight casts in one dispatch ---
  cvt6<<<21120, 256, 0, stream>>>(w1, w1b, w2, w2b, ipw, ipb, xpw, xpb, dtw, dtb, opw, opb);

  // --- LN1 -> MLP (256^2 MLP1; 256^2 split-K x4 MLP2) -> combine+LN2 ---
  ln_bf16<<<M_ROWS, 256, 0, stream>>>(x, g1, b1, xn);
  gemm256<0><<<dim3(D_INNER / 256, M_ROWS / 256), 512, 0, stream>>>(
      xn, w1b, M_ROWS, D_INNER, D_MODEL, D_MODEL, D_MODEL, bias1, hid);
  gemm256<8><<<dim3(D_MODEL / 256, M_ROWS / 256, 4), 512, 0, stream>>>(
      hid, w2b, M_ROWS, D_MODEL, D_INNER / 4, D_INNER, D_INNER, nullptr, pA);
  combine_ln<<<M_ROWS, 256, 0, stream>>>(pA, bias2, x, g2, b2, x2, xn);

  // --- in_proj (256^2, non-temporal C) -> conv+silu (vectorized) ---
  gemm256<2><<<dim3(2 * D_INNER / 256, M_ROWS / 256), 512, 0, stream>>>(
      xn, ipb, M_ROWS, 2 * D_INNER, D_MODEL, D_MODEL, D_MODEL, nullptr, xz);
  conv_silu_k<<<(size_t)M_ROWS * 512 / 256, 256, 0, stream>>>(xz, cw, cb, ucb);

  // --- x_proj (split-K x8 via blockIdx.z) -> combine ---
  gemm_bt<6><<<dim3(1, M_ROWS / 128, 8), 256, 0, stream>>>(
      ucb, xpb, M_ROWS, 96, 512, D_INNER, D_INNER, 96,
      nullptr, nullptr, xpart);
  xproj_combine<<<M_ROWS * 96 / 256, 256, 0, stream>>>(xpart, dtin, Bmb, Cmb);

  // --- dt_proj + softplus -> bf16 ---
  gemm_bt<4><<<dim3(D_INNER / 128, M_ROWS / 128), 256, 0, stream>>>(
      dtin, dtb, M_ROWS, D_INNER, DT_RANK, DT_RANK, DT_RANK, D_INNER, dtbv, nullptr, dtbf);

  // --- chunk-parallel selective scan (LC=32) -> y (into u-half of xz) ---
  scan_part<<<dim3(D_INNER / 128, NCHUNK, B_SZ), 128, 0, stream>>>(
      dtbf, ucb, Bmb, A_log, Qbuf, sumdt);
  scan_carry<<<B_SZ * D_INNER * 16 / 256, 256, 0, stream>>>(Qbuf, sumdt, A_log);
  scan_final<<<dim3(D_INNER / 128, NCHUNK, B_SZ), 128, 0, stream>>>(
      dtbf, ucb, Bmb, Cmb, xz, A_log, Dvec, Qbuf);

  // --- out_proj (256^2 split-K x4, bf16 partials) + residual -> d_out ---
  gemm256<8><<<dim3(D_MODEL / 256, M_ROWS / 256, 4), 512, 0, stream>>>(
      xz, opb, M_ROWS, D_MODEL, D_INNER / 4, 2 * D_INNER, D_INNER, nullptr, pB);
  splitk_combine_bf<<<M_ROWS * D_MODEL / 1024, 256, 0, stream>>>(pB, x2, (float*)d_out);
}